// Round 3
// baseline (31.262 us; speedup 1.0000x reference)
//
#include <hip/hip_runtime.h>
#include <math.h>

// DynamicTrackHead fused kernel — R3: restructured phase-1 loop nest.
// Key change vs R2: output-channel loop is a *middle* loop (#pragma unroll 2)
// with a 2-row register feature tile, so the live scalar (SGPR) working set is
// ~20 weights instead of 160. Layer-1 is fused into the same o-loop via
// column-accumulation so no runtime-indexed register arrays exist (rule #20).
// Shapes: mask_feats [N=2,8,96,160] f32, 128 instances, params 736/instance:
// w0[8][10] @0, w1[8][8] @80, w2[64][8] @144, b0 @656, b1 @664, b2 @672.
// Output: main_logits[128,64] then side_logits[128,64], f32.

#define H_IN 96
#define W_IN 160
#define HW_IN (H_IN * W_IN)
#define PW 40            // W_IN / 4
#define PH 24            // H_IN / 4
#define NPIX (PH * PW)   // 960 pooled-twice pixels
#define NPARAM 736
#define OW0 0
#define OW1 80
#define OW2 144
#define OB0 656
#define OB1 664
#define OB2 672

#define BLOCK 1024
#define NWAVE (BLOCK / 64)           // 16
#define PIX_PER_WAVE (NPIX / NWAVE)  // 60

#define SELU_SCALE 1.0507009873554805f
#define SELU_ALPHA 1.6732632423543772f

__global__ __launch_bounds__(BLOCK, 4) void track_head_fused(
    const float* __restrict__ mask_feats,
    const float* __restrict__ pmain,
    const float* __restrict__ pside,
    const int*   __restrict__ im_inds,
    const float* __restrict__ inst_loc,
    const float* __restrict__ offset_pred,
    const int*   __restrict__ fpn_levels,
    const float* __restrict__ mw1, const float* __restrict__ mb1,
    const float* __restrict__ mg,  const float* __restrict__ mbeta,
    const float* __restrict__ mw2, const float* __restrict__ mb2,
    const float* __restrict__ sw1, const float* __restrict__ sb1,
    const float* __restrict__ sg,  const float* __restrict__ sbeta,
    const float* __restrict__ sw2, const float* __restrict__ sb2,
    const int*   __restrict__ stride_ptr,
    float*       __restrict__ out,
    int n_inst)
{
    const int inst = blockIdx.x;
    const int head = blockIdx.y;
    const int tid  = threadIdx.x;
    const int lane = tid & 63;
    const int wid  = tid >> 6;

    __shared__ __align__(16) float s_m1[NPIX][8];   // layer-1 pooled outputs (30 KB)
    __shared__ float s_red[NWAVE][64];              // per-wave layer-2 partial sums
    __shared__ __align__(16) float s_x[64];         // spatial mean vector
    __shared__ __align__(16) float s_h[128];        // MLP hidden
    __shared__ float s_r[4];                        // LN reductions

    // Dynamic params: uniform pointer -> scalar loads.
    const float* __restrict__ P = (head ? pside : pmain) + (size_t)inst * NPARAM;

    const int S  = stride_ptr[0];
    const int S2 = S / 2;
    float lx = inst_loc[inst * 2 + 0];
    float ly = inst_loc[inst * 2 + 1];
    if (head) {
        lx += offset_pred[inst * 2 + 0] * 128.0f;
        ly += offset_pred[inst * 2 + 1] * 128.0f;
    }
    const float inv_soi = 1.0f / (float)(64 << fpn_levels[inst]);
    const float* __restrict__ feat =
        mask_feats + (size_t)im_inds[inst] * 8 * HW_IN;

    // ---------------- Phase 1: conv0(relu,pool) + conv1(relu,pool) ----------
    if (tid < NPIX) {
        const int p   = tid;
        const int py  = p / PW;
        const int px  = p - py * PW;
        const int iy0 = py * 4, ix0 = px * 4;

        // x-coordinates of the 4 input columns of this pooled pixel
        float x0v[4];
        #pragma unroll
        for (int j = 0; j < 4; j++)
            x0v[j] = (lx - (float)((ix0 + j) * S + S2)) * inv_soi;

        float m1[8];
        #pragma unroll
        for (int o = 0; o < 8; o++) m1[o] = 0.0f;

        #pragma unroll
        for (int qy = 0; qy < 2; qy++) {
            // ---- load a 2-row x 8-channel register tile (16 float4) ----
            float4 f[2][8];
            float  x1v[2];
            #pragma unroll
            for (int sy = 0; sy < 2; sy++) {
                const int iy = iy0 + qy * 2 + sy;
                x1v[sy] = (ly - (float)(iy * S + S2)) * inv_soi;
                const float* rowp = feat + iy * W_IN + ix0;
                #pragma unroll
                for (int c = 0; c < 8; c++)
                    f[sy][c] = *(const float4*)(rowp + c * HW_IN);
            }

            // layer-1 pre-activation accumulators for the two pool-1 pixels
            // (quadrant a: input cols 0-1, quadrant b: cols 2-3)
            float l1a[8], l1b[8];
            #pragma unroll
            for (int o2 = 0; o2 < 8; o2++) {
                const float b1o = P[OB1 + o2];
                l1a[o2] = b1o;
                l1b[o2] = b1o;
            }

            // ---- conv0 for this tile, one output channel at a time ----
            // NOT fully unrolled: keeps the live scalar set ~2x12 weights.
            #pragma unroll 2
            for (int o = 0; o < 8; o++) {
                const float* w0r = P + OW0 + o * 10;
                const float w0 = w0r[0], w1w = w0r[1];
                const float wc0 = w0r[2], wc1 = w0r[3], wc2 = w0r[4],
                            wc3 = w0r[5], wc4 = w0r[6], wc5 = w0r[7],
                            wc6 = w0r[8], wc7 = w0r[9];
                const float b0o = P[OB0 + o];

                float ma = 0.0f, mb = 0.0f;   // relu'd quadrant maxes (>=0)
                #pragma unroll
                for (int sy = 0; sy < 2; sy++) {
                    const float base = b0o + w1w * x1v[sy];
#define L0_PIX(JJ, COMP, MM)                                                    \
                    {                                                           \
                        float a = base + w0 * x0v[JJ]                           \
                                + wc0 * f[sy][0].COMP + wc1 * f[sy][1].COMP     \
                                + wc2 * f[sy][2].COMP + wc3 * f[sy][3].COMP     \
                                + wc4 * f[sy][4].COMP + wc5 * f[sy][5].COMP     \
                                + wc6 * f[sy][6].COMP + wc7 * f[sy][7].COMP;    \
                        MM = fmaxf(MM, a);                                      \
                    }
                    L0_PIX(0, x, ma)
                    L0_PIX(1, y, ma)
                    L0_PIX(2, z, mb)
                    L0_PIX(3, w, mb)
#undef L0_PIX
                }
                // ma/mb initialized to 0 => relu folded into the max.

                // ---- fused layer-1 column accumulation (o2 static) ----
                #pragma unroll
                for (int o2 = 0; o2 < 8; o2++) {
                    const float w1c = P[OW1 + o2 * 8 + o];
                    l1a[o2] += w1c * ma;
                    l1b[o2] += w1c * mb;
                }
            }

            // ---- relu + pool-2 into m1 ----
            #pragma unroll
            for (int o2 = 0; o2 < 8; o2++)
                m1[o2] = fmaxf(m1[o2],
                               fmaxf(fmaxf(l1a[o2], 0.0f), fmaxf(l1b[o2], 0.0f)));
        }

        float4* dst = (float4*)&s_m1[p][0];
        dst[0] = make_float4(m1[0], m1[1], m1[2], m1[3]);
        dst[1] = make_float4(m1[4], m1[5], m1[6], m1[7]);
    }
    __syncthreads();

    // ---------------- Phase 2: layer 2 (relu) + spatial mean ----------------
    {
        const int o = lane;                       // output channel
        const float4 wa = *(const float4*)(P + OW2 + o * 8);
        const float4 wb = *(const float4*)(P + OW2 + o * 8 + 4);
        const float  bo = P[OB2 + o];
        float accum = 0.0f;
        const int p0 = wid * PIX_PER_WAVE;
        const int p1 = p0 + PIX_PER_WAVE;
        #pragma unroll 4
        for (int p = p0; p < p1; p++) {
            const float4 va = *(const float4*)&s_m1[p][0];   // broadcast read
            const float4 vb = *(const float4*)&s_m1[p][4];
            float a = bo + wa.x * va.x + wa.y * va.y + wa.z * va.z + wa.w * va.w
                         + wb.x * vb.x + wb.y * vb.y + wb.z * vb.z + wb.w * vb.w;
            accum += fmaxf(a, 0.0f);
        }
        s_red[wid][o] = accum;
    }
    __syncthreads();

    if (tid < 64) {
        float xm = 0.0f;
        #pragma unroll
        for (int w = 0; w < NWAVE; w++) xm += s_red[w][tid];
        s_x[tid] = xm * (1.0f / (float)NPIX);
    }
    __syncthreads();

    // ---------------- MLP: fc1 -> LayerNorm -> SELU -> fc2 ------------------
    const float* __restrict__ w1h = head ? sw1 : mw1;
    const float* __restrict__ b1h = head ? sb1 : mb1;
    const float* __restrict__ gh  = head ? sg  : mg;
    const float* __restrict__ bth = head ? sbeta : mbeta;
    const float* __restrict__ w2h = head ? sw2 : mw2;
    const float* __restrict__ b2h = head ? sb2 : mb2;

    float hval = 0.0f, dval = 0.0f;
    if (tid < 128) {
        const float* wr = w1h + tid * 64;
        float a = b1h[tid];
        #pragma unroll
        for (int k = 0; k < 16; k++) {
            const float4 wv = *(const float4*)(wr + k * 4);
            const float4 xv = *(const float4*)(&s_x[k * 4]);
            a += wv.x * xv.x + wv.y * xv.y + wv.z * xv.z + wv.w * xv.w;
        }
        hval = a;
    }
    {
        float s = hval;
        #pragma unroll
        for (int m = 32; m >= 1; m >>= 1) s += __shfl_xor(s, m, 64);
        if (lane == 0 && wid < 2) s_r[wid] = s;
    }
    __syncthreads();
    const float mu = (s_r[0] + s_r[1]) * (1.0f / 128.0f);
    if (tid < 128) dval = hval - mu;
    {
        float s = dval * dval;
        #pragma unroll
        for (int m = 32; m >= 1; m >>= 1) s += __shfl_xor(s, m, 64);
        if (lane == 0 && wid < 2) s_r[wid + 2] = s;
    }
    __syncthreads();
    const float var = (s_r[2] + s_r[3]) * (1.0f / 128.0f);

    if (tid < 128) {
        const float hn = dval * (1.0f / sqrtf(var + 1e-5f)) * gh[tid] + bth[tid];
        const float sv = (hn > 0.0f)
                           ? SELU_SCALE * hn
                           : SELU_SCALE * SELU_ALPHA * (expf(hn) - 1.0f);
        s_h[tid] = sv;
    }
    __syncthreads();

    if (tid < 64) {
        const float* wr = w2h + tid * 128;
        float a = b2h[tid];
        #pragma unroll
        for (int k = 0; k < 32; k++) {
            const float4 wv = *(const float4*)(wr + k * 4);
            const float4 hv = *(const float4*)(&s_h[k * 4]);
            a += wv.x * hv.x + wv.y * hv.y + wv.z * hv.z + wv.w * hv.w;
        }
        out[(size_t)head * (size_t)n_inst * 64 + (size_t)inst * 64 + tid] = a;
    }
}

extern "C" void kernel_launch(void* const* d_in, const int* in_sizes, int n_in,
                              void* d_out, int out_size, void* d_ws, size_t ws_size,
                              hipStream_t stream) {
    const float* mask_feats  = (const float*)d_in[0];
    const float* pmain       = (const float*)d_in[1];
    const float* pside       = (const float*)d_in[2];
    const int*   im_inds     = (const int*)  d_in[3];
    const float* inst_loc    = (const float*)d_in[4];
    const float* offset_pred = (const float*)d_in[5];
    const int*   fpn_levels  = (const int*)  d_in[6];
    const float* mw1   = (const float*)d_in[7];
    const float* mb1   = (const float*)d_in[8];
    const float* mg    = (const float*)d_in[9];
    const float* mbeta = (const float*)d_in[10];
    const float* mw2   = (const float*)d_in[11];
    const float* mb2   = (const float*)d_in[12];
    const float* sw1   = (const float*)d_in[13];
    const float* sb1   = (const float*)d_in[14];
    const float* sg    = (const float*)d_in[15];
    const float* sbeta = (const float*)d_in[16];
    const float* sw2   = (const float*)d_in[17];
    const float* sb2   = (const float*)d_in[18];
    const int*   strid = (const int*)  d_in[19];
    float* out = (float*)d_out;

    const int n_inst = in_sizes[3];   // im_inds length

    dim3 grid(n_inst, 2);
    track_head_fused<<<grid, BLOCK, 0, stream>>>(
        mask_feats, pmain, pside, im_inds, inst_loc, offset_pred, fpn_levels,
        mw1, mb1, mg, mbeta, mw2, mb2,
        sw1, sb1, sg, sbeta, sw2, sb2,
        strid, out, n_inst);
}

// Round 4
// 27.404 us; speedup vs baseline: 1.1408x; 1.1408x over previous
//
#include <hip/hip_runtime.h>
#include <math.h>

// DynamicTrackHead — R4: two-kernel split, single-wave K1 blocks.
// K1: grid (n_inst, 2, 15), block 64. Each block = 64 pooled pixels of one
//     (inst, head): conv0(relu,pool2) + conv1(relu,pool2) + conv2(relu) +
//     partial spatial sum -> 64-float partial to d_ws.
//     Single wave => no __syncthreads coupling; 15 independent waves/CU.
// K2: grid (n_inst, 2), block 128. Sum 15 partials -> mean -> MLP -> out.
// params per instance = 736 floats: w0[8][10]@0, w1[8][8]@80, w2[64][8]@144,
// b0@656, b1@664, b2@672.

#define H_IN 96
#define W_IN 160
#define HW_IN (H_IN * W_IN)
#define PW 40            // W_IN / 4
#define PH 24            // H_IN / 4
#define NPIX (PH * PW)   // 960 pooled-twice pixels
#define NCHUNK 15        // K1 blocks per (inst,head)
#define CPIX 64          // pixels per K1 block
#define NPARAM 736
#define OW0 0
#define OW1 80
#define OW2 144
#define OB0 656
#define OB1 664
#define OB2 672

#define SELU_SCALE 1.0507009873554805f
#define SELU_ALPHA 1.6732632423543772f

// ---------------------------------------------------------------------------
// K1: conv tower + partial spatial sum. One wave per block.
// ---------------------------------------------------------------------------
__global__ __launch_bounds__(64, 4) void track_head_conv(
    const float* __restrict__ mask_feats,
    const float* __restrict__ pmain,
    const float* __restrict__ pside,
    const int*   __restrict__ im_inds,
    const float* __restrict__ inst_loc,
    const float* __restrict__ offset_pred,
    const int*   __restrict__ fpn_levels,
    const int*   __restrict__ stride_ptr,
    float*       __restrict__ ws_part)      // [n_inst][2][NCHUNK][64]
{
    const int inst  = blockIdx.x;
    const int head  = blockIdx.y;
    const int chunk = blockIdx.z;
    const int tid   = threadIdx.x;          // 0..63

    __shared__ __align__(16) float s_m1[CPIX][8];   // 2 KB

    const float* __restrict__ P = (head ? pside : pmain) + (size_t)inst * NPARAM;

    const int S  = stride_ptr[0];
    const int S2 = S / 2;
    float lx = inst_loc[inst * 2 + 0];
    float ly = inst_loc[inst * 2 + 1];
    if (head) {
        lx += offset_pred[inst * 2 + 0] * 128.0f;
        ly += offset_pred[inst * 2 + 1] * 128.0f;
    }
    const float inv_soi = 1.0f / (float)(64 << fpn_levels[inst]);
    const float* __restrict__ feat =
        mask_feats + (size_t)im_inds[inst] * 8 * HW_IN;

    // ---- conv0 (relu, pool2) + conv1 (relu, pool2) for one pooled pixel ----
    {
        const int p   = chunk * CPIX + tid;   // 0..959
        const int py  = p / PW;
        const int px  = p - py * PW;
        const int iy0 = py * 4, ix0 = px * 4;

        float x0v[4];
        #pragma unroll
        for (int j = 0; j < 4; j++)
            x0v[j] = (lx - (float)((ix0 + j) * S + S2)) * inv_soi;

        float m1[8];
        #pragma unroll
        for (int o = 0; o < 8; o++) m1[o] = 0.0f;

        #pragma unroll
        for (int qy = 0; qy < 2; qy++) {
            float m0a[8], m0b[8];     // quadrant relu'd maxes (>= 0)
            #pragma unroll
            for (int o = 0; o < 8; o++) { m0a[o] = 0.0f; m0b[o] = 0.0f; }

            #pragma unroll
            for (int sy = 0; sy < 2; sy++) {
                const int iy = iy0 + qy * 2 + sy;
                const float x1 = (ly - (float)(iy * S + S2)) * inv_soi;
                const float* rowp = feat + iy * W_IN + ix0;
                const float4 f0 = *(const float4*)(rowp + 0 * HW_IN);
                const float4 f1 = *(const float4*)(rowp + 1 * HW_IN);
                const float4 f2 = *(const float4*)(rowp + 2 * HW_IN);
                const float4 f3 = *(const float4*)(rowp + 3 * HW_IN);
                const float4 f4 = *(const float4*)(rowp + 4 * HW_IN);
                const float4 f5 = *(const float4*)(rowp + 5 * HW_IN);
                const float4 f6 = *(const float4*)(rowp + 6 * HW_IN);
                const float4 f7 = *(const float4*)(rowp + 7 * HW_IN);

#define L0_PIX(JJ, COMP, M0ARR)                                                 \
                {                                                               \
                    const float x0 = x0v[JJ];                                   \
                    _Pragma("unroll")                                           \
                    for (int o = 0; o < 8; o++) {                               \
                        const float* w0r = P + OW0 + o * 10;                    \
                        float a = P[OB0 + o] + w0r[0] * x0 + w0r[1] * x1        \
                                + w0r[2] * f0.COMP + w0r[3] * f1.COMP           \
                                + w0r[4] * f2.COMP + w0r[5] * f3.COMP           \
                                + w0r[6] * f4.COMP + w0r[7] * f5.COMP           \
                                + w0r[8] * f6.COMP + w0r[9] * f7.COMP;          \
                        M0ARR[o] = fmaxf(M0ARR[o], a);                          \
                    }                                                           \
                }
                L0_PIX(0, x, m0a)
                L0_PIX(1, y, m0a)
                L0_PIX(2, z, m0b)
                L0_PIX(3, w, m0b)
#undef L0_PIX
            }

            // layer 1 on the two quadrant maxes, pool into m1
            #pragma unroll
            for (int o = 0; o < 8; o++) {
                float a = P[OB1 + o];
                float b = a;
                #pragma unroll
                for (int c = 0; c < 8; c++) {
                    const float w = P[OW1 + o * 8 + c];
                    a += w * m0a[c];
                    b += w * m0b[c];
                }
                m1[o] = fmaxf(m1[o], fmaxf(fmaxf(a, 0.0f), fmaxf(b, 0.0f)));
            }
        }
        float4* dst = (float4*)&s_m1[tid][0];
        dst[0] = make_float4(m1[0], m1[1], m1[2], m1[3]);
        dst[1] = make_float4(m1[4], m1[5], m1[6], m1[7]);
    }
    __syncthreads();   // single wave: compiles to a waitcnt, no barrier stall

    // ---- conv2 (relu) + partial sum over this block's 64 pixels ----
    {
        const int o = tid;                    // output channel 0..63
        const float4 wa = *(const float4*)(P + OW2 + o * 8);
        const float4 wb = *(const float4*)(P + OW2 + o * 8 + 4);
        const float  bo = P[OB2 + o];
        float accum = 0.0f;
        #pragma unroll 4
        for (int p2 = 0; p2 < CPIX; p2++) {
            const float4 va = *(const float4*)&s_m1[p2][0];   // broadcast read
            const float4 vb = *(const float4*)&s_m1[p2][4];
            float a = bo + wa.x * va.x + wa.y * va.y + wa.z * va.z + wa.w * va.w
                         + wb.x * vb.x + wb.y * vb.y + wb.z * vb.z + wb.w * vb.w;
            accum += fmaxf(a, 0.0f);
        }
        ws_part[(((size_t)inst * 2 + head) * NCHUNK + chunk) * 64 + o] = accum;
    }
}

// ---------------------------------------------------------------------------
// K2: combine partials -> mean -> MLP (fc1 -> LN -> SELU -> fc2) -> logits
// ---------------------------------------------------------------------------
__global__ __launch_bounds__(128) void track_head_mlp(
    const float* __restrict__ ws_part,
    const float* __restrict__ mw1, const float* __restrict__ mb1,
    const float* __restrict__ mg,  const float* __restrict__ mbeta,
    const float* __restrict__ mw2, const float* __restrict__ mb2,
    const float* __restrict__ sw1, const float* __restrict__ sb1,
    const float* __restrict__ sg,  const float* __restrict__ sbeta,
    const float* __restrict__ sw2, const float* __restrict__ sb2,
    float*       __restrict__ out,
    int n_inst)
{
    const int inst = blockIdx.x;
    const int head = blockIdx.y;
    const int tid  = threadIdx.x;
    const int lane = tid & 63;
    const int wid  = tid >> 6;

    __shared__ __align__(16) float s_x[64];
    __shared__ __align__(16) float s_h[128];
    __shared__ float s_r[4];

    if (tid < 64) {
        const float* base = ws_part + ((size_t)inst * 2 + head) * NCHUNK * 64 + tid;
        float xm = 0.0f;
        #pragma unroll
        for (int q = 0; q < NCHUNK; q++) xm += base[q * 64];
        s_x[tid] = xm * (1.0f / (float)NPIX);
    }
    __syncthreads();

    const float* __restrict__ w1h = head ? sw1 : mw1;
    const float* __restrict__ b1h = head ? sb1 : mb1;
    const float* __restrict__ gh  = head ? sg  : mg;
    const float* __restrict__ bth = head ? sbeta : mbeta;
    const float* __restrict__ w2h = head ? sw2 : mw2;
    const float* __restrict__ b2h = head ? sb2 : mb2;

    float hval = 0.0f, dval = 0.0f;
    {
        const float* wr = w1h + tid * 64;
        float a = b1h[tid];
        #pragma unroll
        for (int k = 0; k < 16; k++) {
            const float4 wv = *(const float4*)(wr + k * 4);
            const float4 xv = *(const float4*)(&s_x[k * 4]);
            a += wv.x * xv.x + wv.y * xv.y + wv.z * xv.z + wv.w * xv.w;
        }
        hval = a;
    }
    {
        float s = hval;
        #pragma unroll
        for (int m = 32; m >= 1; m >>= 1) s += __shfl_xor(s, m, 64);
        if (lane == 0) s_r[wid] = s;
    }
    __syncthreads();
    const float mu = (s_r[0] + s_r[1]) * (1.0f / 128.0f);
    dval = hval - mu;
    {
        float s = dval * dval;
        #pragma unroll
        for (int m = 32; m >= 1; m >>= 1) s += __shfl_xor(s, m, 64);
        if (lane == 0) s_r[wid + 2] = s;
    }
    __syncthreads();
    const float var = (s_r[2] + s_r[3]) * (1.0f / 128.0f);

    {
        const float hn = dval * (1.0f / sqrtf(var + 1e-5f)) * gh[tid] + bth[tid];
        const float sv = (hn > 0.0f)
                           ? SELU_SCALE * hn
                           : SELU_SCALE * SELU_ALPHA * (expf(hn) - 1.0f);
        s_h[tid] = sv;
    }
    __syncthreads();

    if (tid < 64) {
        const float* wr = w2h + tid * 128;
        float a = b2h[tid];
        #pragma unroll
        for (int k = 0; k < 32; k++) {
            const float4 wv = *(const float4*)(wr + k * 4);
            const float4 hv = *(const float4*)(&s_h[k * 4]);
            a += wv.x * hv.x + wv.y * hv.y + wv.z * hv.z + wv.w * hv.w;
        }
        out[(size_t)head * (size_t)n_inst * 64 + (size_t)inst * 64 + tid] = a;
    }
}

extern "C" void kernel_launch(void* const* d_in, const int* in_sizes, int n_in,
                              void* d_out, int out_size, void* d_ws, size_t ws_size,
                              hipStream_t stream) {
    const float* mask_feats  = (const float*)d_in[0];
    const float* pmain       = (const float*)d_in[1];
    const float* pside       = (const float*)d_in[2];
    const int*   im_inds     = (const int*)  d_in[3];
    const float* inst_loc    = (const float*)d_in[4];
    const float* offset_pred = (const float*)d_in[5];
    const int*   fpn_levels  = (const int*)  d_in[6];
    const float* mw1   = (const float*)d_in[7];
    const float* mb1   = (const float*)d_in[8];
    const float* mg    = (const float*)d_in[9];
    const float* mbeta = (const float*)d_in[10];
    const float* mw2   = (const float*)d_in[11];
    const float* mb2   = (const float*)d_in[12];
    const float* sw1   = (const float*)d_in[13];
    const float* sb1   = (const float*)d_in[14];
    const float* sg    = (const float*)d_in[15];
    const float* sbeta = (const float*)d_in[16];
    const float* sw2   = (const float*)d_in[17];
    const float* sb2   = (const float*)d_in[18];
    const int*   strid = (const int*)  d_in[19];
    float* out = (float*)d_out;

    const int n_inst = in_sizes[3];   // im_inds length
    float* ws_part = (float*)d_ws;    // n_inst*2*NCHUNK*64 floats = 983 KB

    dim3 g1(n_inst, 2, NCHUNK);
    track_head_conv<<<g1, CPIX, 0, stream>>>(
        mask_feats, pmain, pside, im_inds, inst_loc, offset_pred, fpn_levels,
        strid, ws_part);

    dim3 g2(n_inst, 2);
    track_head_mlp<<<g2, 128, 0, stream>>>(
        ws_part,
        mw1, mb1, mg, mbeta, mw2, mb2,
        sw1, sb1, sg, sbeta, sw2, sb2,
        out, n_inst);
}